// Round 6
// baseline (390.080 us; speedup 1.0000x reference)
//
#include <hip/hip_runtime.h>
#include <hip/hip_bf16.h>
#include <math.h>

#define NEG_SLOPE 0.2f
#define GAT_EPS 1e-16f

constexpr int NN = 50000;   // nodes
constexpr int NE = 800000;  // raw edges
constexpr int EP = NE + NN; // edges incl. self loops = 850000
constexpr int NB = (NN + 255) / 256; // scan blocks = 196

// CSR-build geometry
constexpr int PB  = 128;                  // histogram blocks
constexpr int PT  = 1024;                 // threads per histogram block
constexpr int CH  = (EP + PB - 1) / PB;   // edges per block = 6641
constexpr int NCH = 4;                    // block-row chunks
constexpr int BPC = PB / NCH;             // 32 block-rows per chunk

__device__ inline void edge_sd(const int* __restrict__ ei, int i, int& s, int& d) {
    if (i < NE) { s = ei[i]; d = ei[NE + i]; }
    else        { s = d = i - NE; }
}

__device__ inline float bflo(unsigned int h) { return __uint_as_float(h << 16); }
__device__ inline float bfhi(unsigned int h) { return __uint_as_float(h & 0xffff0000u); }

// ---------------- CSR build, zero device-scope atomics ----------------
__global__ __launch_bounds__(PT) void k_p1_hist(const int* __restrict__ ei,
                                                float* __restrict__ out0,
                                                unsigned char* __restrict__ hist,
                                                unsigned char* __restrict__ rank8) {
    __shared__ unsigned int sh[NN / 4]; // 12500 words = 50KB
    int b = blockIdx.x, t = threadIdx.x;
    for (int w = t; w < NN / 4; w += PT) sh[w] = 0u;
    __syncthreads();
    int i0 = b * CH;
    int iend = i0 + CH; if (iend > EP) iend = EP;
    for (int i = i0 + t; i < iend; i += PT) {
        int s, d; edge_sd(ei, i, s, d);
        __builtin_nontemporal_store((float)s, &out0[i]);
        __builtin_nontemporal_store((float)d, &out0[EP + i]);
        int sft = (d & 3) * 8;
        unsigned int old = atomicAdd(&sh[d >> 2], 1u << sft); // LDS atomic, CU-local
        __builtin_nontemporal_store((unsigned char)(old >> sft), &rank8[i]);
    }
    __syncthreads();
    unsigned int* hw = (unsigned int*)(hist + (size_t)b * NN);
    for (int w = t; w < NN / 4; w += PT) hw[w] = sh[w];
}

// Fused p2+scan1: register-pipelined column scan of all PB hist rows per node,
// packed chunkoff, then block scan of per-node totals.
__global__ __launch_bounds__(256) void k_p2s1(unsigned char* __restrict__ hist,
                                              unsigned char* __restrict__ chunkoff,
                                              int* __restrict__ rowptr,
                                              int* __restrict__ bsum) {
    __shared__ int sh[256];
    int t = threadIdx.x;
    int n = blockIdx.x * 256 + t;
    int v = 0;
    if (n < NN) {
        unsigned int runs[NCH];
#pragma unroll
        for (int c = 0; c < NCH; ++c) {
            size_t base = (size_t)(c * BPC) * NN + n;
            unsigned int vv[BPC];
#pragma unroll
            for (int b = 0; b < BPC; ++b) vv[b] = hist[base + (size_t)b * NN];
            unsigned int run = 0;
#pragma unroll
            for (int b = 0; b < BPC; ++b) { unsigned int x = vv[b]; vv[b] = run; run += x; }
#pragma unroll
            for (int b = 0; b < BPC; ++b) hist[base + (size_t)b * NN] = (unsigned char)vv[b];
            runs[c] = run;
        }
        unsigned int o1 = runs[0], o2 = o1 + runs[1], o3 = o2 + runs[2];
        *(unsigned int*)&chunkoff[(size_t)n * 4] = (o1 << 8) | (o2 << 16) | (o3 << 24);
        v = (int)(o3 + runs[3]);
    }
    sh[t] = v; __syncthreads();
    for (int off = 1; off < 256; off <<= 1) {
        int x = (t >= off) ? sh[t - off] : 0;
        __syncthreads();
        sh[t] += x;
        __syncthreads();
    }
    if (n < NN) rowptr[n] = sh[t] - v;
    if (t == 255) bsum[blockIdx.x] = sh[255];
}

// Fused scan2+scan3: every block redundantly scans bsum in LDS, applies its offset.
__global__ __launch_bounds__(256) void k_s23(int* __restrict__ rowptr,
                                             const int* __restrict__ bsum) {
    __shared__ int sh[256];
    int t = threadIdx.x;
    int v = (t < NB) ? bsum[t] : 0;
    sh[t] = v; __syncthreads();
    for (int off = 1; off < 256; off <<= 1) {
        int x = (t >= off) ? sh[t - off] : 0;
        __syncthreads();
        sh[t] += x;
        __syncthreads();
    }
    int blk = blockIdx.x;
    int off = (blk == 0) ? 0 : sh[blk - 1];
    int n = blk * 256 + t;
    if (n < NN) rowptr[n] += off;
    if (n == 0) rowptr[NN] = EP;
}

// CSR fill, grid-strided for full occupancy.
__global__ __launch_bounds__(256) void k_fill(const int* __restrict__ ei,
                                              const unsigned char* __restrict__ rank8,
                                              const unsigned char* __restrict__ hist,
                                              const unsigned char* __restrict__ chunkoff,
                                              const int* __restrict__ rowptr,
                                              unsigned short* __restrict__ col) {
    int i = blockIdx.x * 256 + threadIdx.x;
    if (i >= EP) return;
    int b = i / CH;   // hist block-row (const divide -> magic mul)
    int c = b / BPC;  // chunk
    int s, d; edge_sd(ei, i, s, d);
    int pos = rowptr[d] + (int)chunkoff[d * 4 + c] + (int)hist[(size_t)b * NN + d]
            + (int)rank8[i];
    col[pos] = (unsigned short)s;
}

// edge-order alpha output (coalesced NT write; score arrays L2-resident)
__global__ void k_alpha_out(const int* __restrict__ ei, const float* __restrict__ as_,
                            const float* __restrict__ ad_, const float* __restrict__ inv,
                            float* __restrict__ out_alpha) {
    int i = blockIdx.x * blockDim.x + threadIdx.x;
    if (i >= EP) return;
    int s, d; edge_sd(ei, i, s, d);
    float v = as_[s] + ad_[d];
    v = v > 0.f ? v : NEG_SLOPE * v;
    __builtin_nontemporal_store(__expf(v) * inv[d], &out_alpha[i]);
}

// ---------------- dense GEMM + fused alpha scores (layer 1 only) ----------------
struct alignas(8) bh4 { __hip_bfloat16 a, b, c, d; };

__device__ inline void fma4(float4& acc, float x, const float4& w) {
    acc.x = fmaf(x, w.x, acc.x);
    acc.y = fmaf(x, w.y, acc.y);
    acc.z = fmaf(x, w.z, acc.z);
    acc.w = fmaf(x, w.w, acc.w);
}

template <int FIN, int FOUT, int NPB>
__global__ __launch_bounds__(256) void k_gemm_t(const float* __restrict__ in,
                                                const float* __restrict__ W,
                                                const float* __restrict__ avs,
                                                const float* __restrict__ avd,
                                                __hip_bfloat16* __restrict__ H,
                                                float* __restrict__ as_,
                                                float* __restrict__ ad_, int n) {
    constexpr int TF = FOUT / 4;
    constexpr int XS = FIN + 4;
    constexpr int WS = FOUT + 4;
    __shared__ float sX[NPB * XS];
    __shared__ float sWt[FIN * WS];
    int tid = threadIdx.x;
    for (int idx = tid; idx < FIN * FOUT; idx += 256) {
        int f = idx % FOUT, k = idx / FOUT;
        sWt[k * WS + f] = W[f * FIN + k];
    }
    int nb = blockIdx.x * NPB;
    for (int idx = tid; idx < NPB * (FIN / 4); idx += 256) {
        int node = idx / (FIN / 4), kq = idx % (FIN / 4);
        int g = nb + node;
        float4 v = make_float4(0.f, 0.f, 0.f, 0.f);
        if (g < n) v = *(const float4*)&in[(size_t)g * FIN + kq * 4];
        *(float4*)&sX[node * XS + kq * 4] = v;
    }
    __syncthreads();

    int fq = tid % TF, ng = tid / TF;
    int n0 = ng * 4;
    float4 acc0 = make_float4(0.f, 0.f, 0.f, 0.f);
    float4 acc1 = acc0, acc2 = acc0, acc3 = acc0;
    for (int k = 0; k < FIN; k += 4) {
        float4 w0 = *(const float4*)&sWt[(k + 0) * WS + fq * 4];
        float4 w1 = *(const float4*)&sWt[(k + 1) * WS + fq * 4];
        float4 w2 = *(const float4*)&sWt[(k + 2) * WS + fq * 4];
        float4 w3 = *(const float4*)&sWt[(k + 3) * WS + fq * 4];
        float4 x0 = *(const float4*)&sX[(n0 + 0) * XS + k];
        float4 x1 = *(const float4*)&sX[(n0 + 1) * XS + k];
        float4 x2 = *(const float4*)&sX[(n0 + 2) * XS + k];
        float4 x3 = *(const float4*)&sX[(n0 + 3) * XS + k];
        fma4(acc0, x0.x, w0); fma4(acc0, x0.y, w1); fma4(acc0, x0.z, w2); fma4(acc0, x0.w, w3);
        fma4(acc1, x1.x, w0); fma4(acc1, x1.y, w1); fma4(acc1, x1.z, w2); fma4(acc1, x1.w, w3);
        fma4(acc2, x2.x, w0); fma4(acc2, x2.y, w1); fma4(acc2, x2.z, w2); fma4(acc2, x2.w, w3);
        fma4(acc3, x3.x, w0); fma4(acc3, x3.y, w1); fma4(acc3, x3.z, w2); fma4(acc3, x3.w, w3);
    }
    float4 accs[4] = {acc0, acc1, acc2, acc3};
    float4 vs4 = *(const float4*)&avs[fq * 4];
    float4 vd4 = *(const float4*)&avd[fq * 4];
#pragma unroll
    for (int j = 0; j < 4; ++j) {
        int g = nb + n0 + j;
        float ps = accs[j].x * vs4.x + accs[j].y * vs4.y + accs[j].z * vs4.z + accs[j].w * vs4.w;
        float pd = accs[j].x * vd4.x + accs[j].y * vd4.y + accs[j].z * vd4.z + accs[j].w * vd4.w;
#pragma unroll
        for (int off = TF / 2; off; off >>= 1) {
            ps += __shfl_down(ps, off, TF);
            pd += __shfl_down(pd, off, TF);
        }
        if (g < n) {
            if (fq == 0) { as_[g] = ps; ad_[g] = pd; }
            bh4 o;
            o.a = __float2bfloat16(accs[j].x);
            o.b = __float2bfloat16(accs[j].y);
            o.c = __float2bfloat16(accs[j].z);
            o.d = __float2bfloat16(accs[j].w);
            *(bh4*)&H[(size_t)g * FOUT + fq * 4] = o;
        }
    }
}

// ---------------- FUSED attn (FOUT=64 input) + next-layer GEMM ----------------
// After the attn reduce, every lane holds output features 4*(lane&15)..+3 of its
// node. bias+ReLU -> broadcast h via shuffles -> h @ Wn^T (Wn in LDS, [k][f]
// transposed: lane-consecutive reads, 2 lanes/bank = free) -> scores + bf16 Hout.
// Removes the standalone mid-layer GEMM and the 25.6MB agg round-trip.
template <int GOUT, bool WRITE_INV>
__global__ __launch_bounds__(256) void k_attn_gemm(
    const int* __restrict__ rowptr, const unsigned short* __restrict__ col,
    const float* __restrict__ as_, const float* __restrict__ ad_,
    const __hip_bfloat16* __restrict__ H, const float* __restrict__ bias,
    const float* __restrict__ Wn,   // [GOUT][64]
    const float* __restrict__ avs, const float* __restrict__ avd, // [GOUT]
    __hip_bfloat16* __restrict__ Hout,  // [NN][GOUT]
    float* __restrict__ as_out, float* __restrict__ ad_out,
    float* __restrict__ inv_out) {
    __shared__ float sW[64 * GOUT]; // transposed [k][f]
    int tid = threadIdx.x;
    for (int idx = tid; idx < 64 * GOUT; idx += 256) {
        int f = idx % GOUT, k = idx / GOUT;
        sW[k * GOUT + f] = Wn[f * 64 + k];
    }
    __syncthreads();

    int wid = (blockIdx.x * blockDim.x + tid) >> 6; // node
    int lane = tid & 63;
    if (wid >= NN) return;
    int start = rowptr[wid], end = rowptr[wid + 1];
    float adv = ad_[wid];
    const uint2* __restrict__ H4 = (const uint2*)H;

    float sloc = 0.f;
    float ax = 0.f, ay = 0.f, az = 0.f, aw = 0.f;
    for (int c = start; c < end; c += 64) {
        int e = c + lane;
        float p = 0.f;
        int sc = 0;
        if (e < end) {
            sc = (int)col[e];
            float v = as_[sc] + adv;
            v = v > 0.f ? v : NEG_SLOPE * v;
            p = __expf(v);
        }
        sloc += p;
        int cnt = end - c; if (cnt > 64) cnt = 64;
        int q = lane >> 4, fl = lane & 15;      // row = 16 uint2
        int j = 0;
        for (; j + 32 <= cnt; j += 32) {        // 8 gathers in flight / lane
            float pp[8]; int ss[8]; uint2 hh[8];
#pragma unroll
            for (int k = 0; k < 8; ++k) {
                int ek = j + 4 * k + q;
                pp[k] = __shfl(p, ek);
                ss[k] = __shfl(sc, ek);
            }
#pragma unroll
            for (int k = 0; k < 8; ++k) hh[k] = H4[((size_t)ss[k] << 4) + fl];
#pragma unroll
            for (int k = 0; k < 8; ++k) {
                ax = fmaf(pp[k], bflo(hh[k].x), ax);
                ay = fmaf(pp[k], bfhi(hh[k].x), ay);
                az = fmaf(pp[k], bflo(hh[k].y), az);
                aw = fmaf(pp[k], bfhi(hh[k].y), aw);
            }
        }
        for (; j + 8 <= cnt; j += 8) {
            int e0 = j + q, e1 = j + 4 + q;
            float p0 = __shfl(p, e0), p1 = __shfl(p, e1);
            int s0 = __shfl(sc, e0), s1 = __shfl(sc, e1);
            uint2 h0 = H4[((size_t)s0 << 4) + fl];
            uint2 h1 = H4[((size_t)s1 << 4) + fl];
            ax = fmaf(p0, bflo(h0.x), ax); ay = fmaf(p0, bfhi(h0.x), ay);
            az = fmaf(p0, bflo(h0.y), az); aw = fmaf(p0, bfhi(h0.y), aw);
            ax = fmaf(p1, bflo(h1.x), ax); ay = fmaf(p1, bfhi(h1.x), ay);
            az = fmaf(p1, bflo(h1.y), az); aw = fmaf(p1, bfhi(h1.y), aw);
        }
        for (; j < cnt; j += 4) {
            int e0 = j + q;
            float p0 = __shfl(p, e0);
            int   s0 = __shfl(sc, e0);
            uint2 h0 = H4[((size_t)s0 << 4) + fl];
            ax = fmaf(p0, bflo(h0.x), ax); ay = fmaf(p0, bfhi(h0.x), ay);
            az = fmaf(p0, bflo(h0.y), az); aw = fmaf(p0, bfhi(h0.y), aw);
        }
    }
    for (int off = 32; off; off >>= 1) sloc += __shfl_xor(sloc, off);
    float inv = 1.f / (sloc + GAT_EPS);
    if (WRITE_INV && lane == 0) inv_out[wid] = inv;

    // full feature reduce: all lanes end with features 4*(lane&15)..+3
    ax += __shfl_xor(ax, 16); ay += __shfl_xor(ay, 16);
    az += __shfl_xor(az, 16); aw += __shfl_xor(aw, 16);
    ax += __shfl_xor(ax, 32); ay += __shfl_xor(ay, 32);
    az += __shfl_xor(az, 32); aw += __shfl_xor(aw, 32);

    // bias + ReLU -> h (layer input for the fused GEMM)
    int fl = lane & 15;
    float4 bb = *(const float4*)&bias[fl * 4];
    float h0 = fmaxf(bb.x + ax * inv, 0.f);
    float h1 = fmaxf(bb.y + ay * inv, 0.f);
    float h2 = fmaxf(bb.z + az * inv, 0.f);
    float h3 = fmaxf(bb.w + aw * inv, 0.f);

    // fused h @ Wn^T
    float acc = 0.f;
    if (GOUT == 64) {
        int f = lane;
#pragma unroll
        for (int m = 0; m < 16; ++m) {          // lane m holds features 4m..4m+3
            float q0 = __shfl(h0, m), q1 = __shfl(h1, m);
            float q2 = __shfl(h2, m), q3 = __shfl(h3, m);
            acc = fmaf(q0, sW[(4 * m + 0) * 64 + f], acc);
            acc = fmaf(q1, sW[(4 * m + 1) * 64 + f], acc);
            acc = fmaf(q2, sW[(4 * m + 2) * 64 + f], acc);
            acc = fmaf(q3, sW[(4 * m + 3) * 64 + f], acc);
        }
    } else { // GOUT == 32: split-k across lane halves
        int f = lane & 31, kh = lane >> 5;
#pragma unroll
        for (int mm = 0; mm < 8; ++mm) {
            int m = 8 * kh + mm;
            float q0 = __shfl(h0, m), q1 = __shfl(h1, m);
            float q2 = __shfl(h2, m), q3 = __shfl(h3, m);
            acc = fmaf(q0, sW[(4 * m + 0) * 32 + f], acc);
            acc = fmaf(q1, sW[(4 * m + 1) * 32 + f], acc);
            acc = fmaf(q2, sW[(4 * m + 2) * 32 + f], acc);
            acc = fmaf(q3, sW[(4 * m + 3) * 32 + f], acc);
        }
        acc += __shfl_xor(acc, 32);             // both halves now hold full sum
    }

    // alpha scores of the next layer (linear output, no bias — matches gemm_t)
    float ps, pd;
    if (GOUT == 64) {
        ps = acc * avs[lane];
        pd = acc * avd[lane];
    } else {
        ps = (lane < 32) ? acc * avs[lane] : 0.f;
        pd = (lane < 32) ? acc * avd[lane] : 0.f;
    }
#pragma unroll
    for (int off = 32; off; off >>= 1) {
        ps += __shfl_xor(ps, off);
        pd += __shfl_xor(pd, off);
    }
    if (lane == 0) { as_out[wid] = ps; ad_out[wid] = pd; }

    // bf16 Hout (2B/lane, contiguous per wave)
    if (GOUT == 64) {
        Hout[(size_t)wid * 64 + lane] = __float2bfloat16(acc);
    } else if (lane < 32) {
        Hout[(size_t)wid * 32 + lane] = __float2bfloat16(acc);
    }
}

// ---------------- final attn (FOUT=32 input), unchanged ----------------
template <int FOUT, bool RELU, bool WRITE_INV>
__global__ __launch_bounds__(256) void k_node_attn(
    const int* __restrict__ rowptr, const unsigned short* __restrict__ col,
    const float* __restrict__ as_, const float* __restrict__ ad_,
    const __hip_bfloat16* __restrict__ H, const float* __restrict__ bias,
    float* __restrict__ outp, float* __restrict__ inv_out) {
    int wid = (blockIdx.x * blockDim.x + threadIdx.x) >> 6; // node
    int lane = threadIdx.x & 63;
    if (wid >= NN) return;
    int start = rowptr[wid], end = rowptr[wid + 1];
    float adv = ad_[wid];
    const uint2* __restrict__ H4 = (const uint2*)H;

    float sloc = 0.f;
    float ax = 0.f, ay = 0.f, az = 0.f, aw = 0.f;
    for (int c = start; c < end; c += 64) {
        int e = c + lane;
        float p = 0.f;
        int sc = 0;
        if (e < end) {
            sc = (int)col[e];
            float v = as_[sc] + adv;
            v = v > 0.f ? v : NEG_SLOPE * v;
            p = __expf(v);
        }
        sloc += p;
        int cnt = end - c; if (cnt > 64) cnt = 64;
        if (FOUT == 64) {
            int q = lane >> 4, fl = lane & 15;
            int j = 0;
            for (; j + 32 <= cnt; j += 32) {
                float pp[8]; int ss[8]; uint2 hh[8];
#pragma unroll
                for (int k = 0; k < 8; ++k) {
                    int ek = j + 4 * k + q;
                    pp[k] = __shfl(p, ek);
                    ss[k] = __shfl(sc, ek);
                }
#pragma unroll
                for (int k = 0; k < 8; ++k) hh[k] = H4[((size_t)ss[k] << 4) + fl];
#pragma unroll
                for (int k = 0; k < 8; ++k) {
                    ax = fmaf(pp[k], bflo(hh[k].x), ax);
                    ay = fmaf(pp[k], bfhi(hh[k].x), ay);
                    az = fmaf(pp[k], bflo(hh[k].y), az);
                    aw = fmaf(pp[k], bfhi(hh[k].y), aw);
                }
            }
            for (; j < cnt; j += 4) {
                int e0 = j + q;
                float p0 = __shfl(p, e0);
                int   s0 = __shfl(sc, e0);
                uint2 h0 = H4[((size_t)s0 << 4) + fl];
                ax = fmaf(p0, bflo(h0.x), ax); ay = fmaf(p0, bfhi(h0.x), ay);
                az = fmaf(p0, bflo(h0.y), az); aw = fmaf(p0, bfhi(h0.y), aw);
            }
        } else { // FOUT == 32: row = 8 uint2, 8 edges/step
            int oc = lane >> 3, fl = lane & 7;
            int j = 0;
            for (; j + 32 <= cnt; j += 32) {
                float pp[4]; int ss[4]; uint2 hh[4];
#pragma unroll
                for (int k = 0; k < 4; ++k) {
                    int ek = j + 8 * k + oc;
                    pp[k] = __shfl(p, ek);
                    ss[k] = __shfl(sc, ek);
                }
#pragma unroll
                for (int k = 0; k < 4; ++k) hh[k] = H4[((size_t)ss[k] << 3) + fl];
#pragma unroll
                for (int k = 0; k < 4; ++k) {
                    ax = fmaf(pp[k], bflo(hh[k].x), ax);
                    ay = fmaf(pp[k], bfhi(hh[k].x), ay);
                    az = fmaf(pp[k], bflo(hh[k].y), az);
                    aw = fmaf(pp[k], bfhi(hh[k].y), aw);
                }
            }
            for (; j < cnt; j += 8) {
                int e0 = j + oc;
                float p0 = __shfl(p, e0);
                int   s0 = __shfl(sc, e0);
                uint2 h0 = H4[((size_t)s0 << 3) + fl];
                ax = fmaf(p0, bflo(h0.x), ax); ay = fmaf(p0, bfhi(h0.x), ay);
                az = fmaf(p0, bflo(h0.y), az); aw = fmaf(p0, bfhi(h0.y), aw);
            }
        }
    }
    for (int off = 32; off; off >>= 1) sloc += __shfl_xor(sloc, off);
    float inv = 1.f / (sloc + GAT_EPS);
    if (WRITE_INV && lane == 0) inv_out[wid] = inv;

    if (FOUT == 64) {
        ax += __shfl_xor(ax, 16); ay += __shfl_xor(ay, 16);
        az += __shfl_xor(az, 16); aw += __shfl_xor(aw, 16);
        ax += __shfl_xor(ax, 32); ay += __shfl_xor(ay, 32);
        az += __shfl_xor(az, 32); aw += __shfl_xor(aw, 32);
        if (lane < 16) {
            float4 bb = *(const float4*)&bias[lane * 4];
            float o0 = bb.x + ax * inv;
            float o1 = bb.y + ay * inv;
            float o2 = bb.z + az * inv;
            float o3 = bb.w + aw * inv;
            if (RELU) {
                o0 = fmaxf(o0, 0.f); o1 = fmaxf(o1, 0.f);
                o2 = fmaxf(o2, 0.f); o3 = fmaxf(o3, 0.f);
            }
            *(float4*)&outp[((size_t)wid << 6) + lane * 4] = make_float4(o0, o1, o2, o3);
        }
    } else {
        ax += __shfl_xor(ax, 8);  ay += __shfl_xor(ay, 8);
        az += __shfl_xor(az, 8);  aw += __shfl_xor(aw, 8);
        ax += __shfl_xor(ax, 16); ay += __shfl_xor(ay, 16);
        az += __shfl_xor(az, 16); aw += __shfl_xor(aw, 16);
        ax += __shfl_xor(ax, 32); ay += __shfl_xor(ay, 32);
        az += __shfl_xor(az, 32); aw += __shfl_xor(aw, 32);
        if (lane < 8) {
            float4 bb = *(const float4*)&bias[lane * 4];
            float o0 = bb.x + ax * inv;
            float o1 = bb.y + ay * inv;
            float o2 = bb.z + az * inv;
            float o3 = bb.w + aw * inv;
            if (RELU) {
                o0 = fmaxf(o0, 0.f); o1 = fmaxf(o1, 0.f);
                o2 = fmaxf(o2, 0.f); o3 = fmaxf(o3, 0.f);
            }
            *(float4*)&outp[((size_t)wid << 5) + lane * 4] = make_float4(o0, o1, o2, o3);
        }
    }
}

extern "C" void kernel_launch(void* const* d_in, const int* in_sizes, int n_in,
                              void* d_out, int out_size, void* d_ws, size_t ws_size,
                              hipStream_t stream) {
    const float* x  = (const float*)d_in[0];
    const int*   ei = (const int*)d_in[1];
    const float* W1 = (const float*)d_in[2];
    const float* as1 = (const float*)d_in[3];
    const float* ad1 = (const float*)d_in[4];
    const float* b1 = (const float*)d_in[5];
    const float* W2 = (const float*)d_in[6];
    const float* as2 = (const float*)d_in[7];
    const float* ad2 = (const float*)d_in[8];
    const float* b2 = (const float*)d_in[9];
    const float* W3 = (const float*)d_in[10];
    const float* as3 = (const float*)d_in[11];
    const float* ad3 = (const float*)d_in[12];
    const float* b3 = (const float*)d_in[13];

    float* out = (float*)d_out;
    float* out_edges = out;                 // [2, EP]
    float* out_alpha = out + 2 * EP;        // [EP]
    float* out_final = out + 3 * EP;        // [N, 32] = 6.4MB, written only by attn3

    char* w = (char*)d_ws;
    size_t o = 0;
    auto alloc = [&](size_t bytes) { void* p = w + o; o = (o + bytes + 15) & ~15ull; return p; };
    float* asA = (float*)alloc((size_t)NN * 4);
    float* adA = (float*)alloc((size_t)NN * 4);
    float* asB = (float*)alloc((size_t)NN * 4);
    float* adB = (float*)alloc((size_t)NN * 4);
    float* asC = (float*)alloc((size_t)NN * 4);
    float* adC = (float*)alloc((size_t)NN * 4);
    float* inv = (float*)alloc((size_t)NN * 4);
    __hip_bfloat16* H1 = (__hip_bfloat16*)alloc((size_t)NN * 64 * 2); // 6.4MB
    __hip_bfloat16* H2 = (__hip_bfloat16*)alloc((size_t)NN * 64 * 2); // 6.4MB
    __hip_bfloat16* H3 = (__hip_bfloat16*)alloc((size_t)NN * 32 * 2); // 3.2MB
    int* rowptr = (int*)alloc((size_t)(NN + 1) * 4);
    unsigned char* rank8 = (unsigned char*)alloc((size_t)EP);        // 0.85MB
    unsigned short* col  = (unsigned short*)alloc((size_t)EP * 2);   // 1.7MB
    unsigned char* chunkoff = (unsigned char*)alloc((size_t)NN * 4); // 200KB
    int* bsum = (int*)alloc(1024);

    const size_t histBytes = (size_t)PB * NN;           // 6.4MB
    unsigned char* hist = (ws_size >= o + histBytes)
        ? (unsigned char*)(w + o)
        : (unsigned char*)out_final; // dead until the final attn dispatch

    // --- CSR build: 4 launches ---
    k_p1_hist<<<PB, PT, 0, stream>>>(ei, out_edges, hist, rank8);
    k_p2s1<<<NB, 256, 0, stream>>>(hist, chunkoff, rowptr, bsum);
    k_s23<<<NB, 256, 0, stream>>>(rowptr, bsum);
    k_fill<<<(EP + 255) / 256, 256, 0, stream>>>(ei, rank8, hist, chunkoff, rowptr, col);

    const int nblk = (NN * 64 + 255) / 256;

    // layer 1 GEMM: x @ W1 -> H1 (bf16) + layer-1 scores
    k_gemm_t<128, 64, 64><<<(NN + 63) / 64, 256, 0, stream>>>(x, W1, as1, ad1, H1,
                                                              asA, adA, NN);
    // attn1 + fused gemm2: -> H2 + layer-2 scores + inv
    k_attn_gemm<64, true><<<nblk, 256, 0, stream>>>(rowptr, col, asA, adA, H1, b1,
                                                    W2, as2, ad2, H2, asB, adB, inv);
    // alpha output (layer-1 scores + inv)
    k_alpha_out<<<(EP + 255) / 256, 256, 0, stream>>>(ei, asA, adA, inv, out_alpha);

    // attn2 + fused gemm3: -> H3 + layer-3 scores
    k_attn_gemm<32, false><<<nblk, 256, 0, stream>>>(rowptr, col, asB, adB, H2, b2,
                                                     W3, as3, ad3, H3, asC, adC, nullptr);
    // attn3: final aggregate + bias (no relu) -> out_final
    k_node_attn<32, false, false><<<nblk, 256, 0, stream>>>(rowptr, col, asC, adC, H3, b3,
                                                            out_final, nullptr);
}

// Round 7
// 275.628 us; speedup vs baseline: 1.4152x; 1.4152x over previous
//
#include <hip/hip_runtime.h>
#include <hip/hip_bf16.h>
#include <math.h>

#define NEG_SLOPE 0.2f
#define GAT_EPS 1e-16f

constexpr int NN = 50000;   // nodes
constexpr int NE = 800000;  // raw edges
constexpr int EP = NE + NN; // edges incl. self loops = 850000
constexpr int NB = (NN + 255) / 256; // scan blocks = 196

// CSR-build geometry
constexpr int PB  = 128;                  // histogram blocks
constexpr int PT  = 1024;                 // threads per histogram block
constexpr int CH  = (EP + PB - 1) / PB;   // edges per block = 6641
constexpr int NCH = 4;                    // block-row chunks
constexpr int BPC = PB / NCH;             // 32 block-rows per chunk

__device__ inline void edge_sd(const int* __restrict__ ei, int i, int& s, int& d) {
    if (i < NE) { s = ei[i]; d = ei[NE + i]; }
    else        { s = d = i - NE; }
}

__device__ inline float bflo(unsigned int h) { return __uint_as_float(h << 16); }
__device__ inline float bfhi(unsigned int h) { return __uint_as_float(h & 0xffff0000u); }

// ---------------- CSR build, zero device-scope atomics ----------------
__global__ __launch_bounds__(PT) void k_p1_hist(const int* __restrict__ ei,
                                                float* __restrict__ out0,
                                                unsigned char* __restrict__ hist,
                                                unsigned char* __restrict__ rank8) {
    __shared__ unsigned int sh[NN / 4]; // 12500 words = 50KB
    int b = blockIdx.x, t = threadIdx.x;
    for (int w = t; w < NN / 4; w += PT) sh[w] = 0u;
    __syncthreads();
    int i0 = b * CH;
    int iend = i0 + CH; if (iend > EP) iend = EP;
    for (int i = i0 + t; i < iend; i += PT) {
        int s, d; edge_sd(ei, i, s, d);
        __builtin_nontemporal_store((float)s, &out0[i]);
        __builtin_nontemporal_store((float)d, &out0[EP + i]);
        int sft = (d & 3) * 8;
        unsigned int old = atomicAdd(&sh[d >> 2], 1u << sft); // LDS atomic, CU-local
        __builtin_nontemporal_store((unsigned char)(old >> sft), &rank8[i]);
    }
    __syncthreads();
    unsigned int* hw = (unsigned int*)(hist + (size_t)b * NN);
    for (int w = t; w < NN / 4; w += PT) hw[w] = sh[w];
}

// Fused p2+scan1: register-pipelined column scan of all PB hist rows per node,
// packed chunkoff, then block scan of per-node totals.
__global__ __launch_bounds__(256) void k_p2s1(unsigned char* __restrict__ hist,
                                              unsigned char* __restrict__ chunkoff,
                                              int* __restrict__ rowptr,
                                              int* __restrict__ bsum) {
    __shared__ int sh[256];
    int t = threadIdx.x;
    int n = blockIdx.x * 256 + t;
    int v = 0;
    if (n < NN) {
        unsigned int runs[NCH];
#pragma unroll
        for (int c = 0; c < NCH; ++c) {
            size_t base = (size_t)(c * BPC) * NN + n;
            unsigned int vv[BPC];
#pragma unroll
            for (int b = 0; b < BPC; ++b) vv[b] = hist[base + (size_t)b * NN];
            unsigned int run = 0;
#pragma unroll
            for (int b = 0; b < BPC; ++b) { unsigned int x = vv[b]; vv[b] = run; run += x; }
#pragma unroll
            for (int b = 0; b < BPC; ++b) hist[base + (size_t)b * NN] = (unsigned char)vv[b];
            runs[c] = run;
        }
        unsigned int o1 = runs[0], o2 = o1 + runs[1], o3 = o2 + runs[2];
        *(unsigned int*)&chunkoff[(size_t)n * 4] = (o1 << 8) | (o2 << 16) | (o3 << 24);
        v = (int)(o3 + runs[3]);
    }
    sh[t] = v; __syncthreads();
    for (int off = 1; off < 256; off <<= 1) {
        int x = (t >= off) ? sh[t - off] : 0;
        __syncthreads();
        sh[t] += x;
        __syncthreads();
    }
    if (n < NN) rowptr[n] = sh[t] - v;
    if (t == 255) bsum[blockIdx.x] = sh[255];
}

// Fused scan2+scan3: every block redundantly scans bsum in LDS, applies its offset.
__global__ __launch_bounds__(256) void k_s23(int* __restrict__ rowptr,
                                             const int* __restrict__ bsum) {
    __shared__ int sh[256];
    int t = threadIdx.x;
    int v = (t < NB) ? bsum[t] : 0;
    sh[t] = v; __syncthreads();
    for (int off = 1; off < 256; off <<= 1) {
        int x = (t >= off) ? sh[t - off] : 0;
        __syncthreads();
        sh[t] += x;
        __syncthreads();
    }
    int blk = blockIdx.x;
    int off = (blk == 0) ? 0 : sh[blk - 1];
    int n = blk * 256 + t;
    if (n < NN) rowptr[n] += off;
    if (n == 0) rowptr[NN] = EP;
}

// CSR fill, grid-strided for full occupancy.
__global__ __launch_bounds__(256) void k_fill(const int* __restrict__ ei,
                                              const unsigned char* __restrict__ rank8,
                                              const unsigned char* __restrict__ hist,
                                              const unsigned char* __restrict__ chunkoff,
                                              const int* __restrict__ rowptr,
                                              unsigned short* __restrict__ col) {
    int i = blockIdx.x * 256 + threadIdx.x;
    if (i >= EP) return;
    int b = i / CH;   // hist block-row (const divide -> magic mul)
    int c = b / BPC;  // chunk
    int s, d; edge_sd(ei, i, s, d);
    int pos = rowptr[d] + (int)chunkoff[d * 4 + c] + (int)hist[(size_t)b * NN + d]
            + (int)rank8[i];
    col[pos] = (unsigned short)s;
}

// edge-order alpha output (coalesced NT write; score arrays L2-resident)
__global__ void k_alpha_out(const int* __restrict__ ei, const float* __restrict__ as_,
                            const float* __restrict__ ad_, const float* __restrict__ inv,
                            float* __restrict__ out_alpha) {
    int i = blockIdx.x * blockDim.x + threadIdx.x;
    if (i >= EP) return;
    int s, d; edge_sd(ei, i, s, d);
    float v = as_[s] + ad_[d];
    v = v > 0.f ? v : NEG_SLOPE * v;
    __builtin_nontemporal_store(__expf(v) * inv[d], &out_alpha[i]);
}

// ---------------- dense GEMM + fused alpha scores ----------------
struct alignas(8) bh4 { __hip_bfloat16 a, b, c, d; };

__device__ inline void fma4(float4& acc, float x, const float4& w) {
    acc.x = fmaf(x, w.x, acc.x);
    acc.y = fmaf(x, w.y, acc.y);
    acc.z = fmaf(x, w.z, acc.z);
    acc.w = fmaf(x, w.w, acc.w);
}

template <int FIN, int FOUT, int NPB>
__global__ __launch_bounds__(256) void k_gemm_t(const float* __restrict__ in,
                                                const float* __restrict__ W,
                                                const float* __restrict__ avs,
                                                const float* __restrict__ avd,
                                                __hip_bfloat16* __restrict__ H,
                                                float* __restrict__ as_,
                                                float* __restrict__ ad_, int n) {
    constexpr int TF = FOUT / 4;
    constexpr int XS = FIN + 4;
    constexpr int WS = FOUT + 4;
    __shared__ float sX[NPB * XS];
    __shared__ float sWt[FIN * WS];
    int tid = threadIdx.x;
    for (int idx = tid; idx < FIN * FOUT; idx += 256) {
        int f = idx % FOUT, k = idx / FOUT;
        sWt[k * WS + f] = W[f * FIN + k];
    }
    int nb = blockIdx.x * NPB;
    for (int idx = tid; idx < NPB * (FIN / 4); idx += 256) {
        int node = idx / (FIN / 4), kq = idx % (FIN / 4);
        int g = nb + node;
        float4 v = make_float4(0.f, 0.f, 0.f, 0.f);
        if (g < n) v = *(const float4*)&in[(size_t)g * FIN + kq * 4];
        *(float4*)&sX[node * XS + kq * 4] = v;
    }
    __syncthreads();

    int fq = tid % TF, ng = tid / TF;
    int n0 = ng * 4;
    float4 acc0 = make_float4(0.f, 0.f, 0.f, 0.f);
    float4 acc1 = acc0, acc2 = acc0, acc3 = acc0;
    for (int k = 0; k < FIN; k += 4) {
        float4 w0 = *(const float4*)&sWt[(k + 0) * WS + fq * 4];
        float4 w1 = *(const float4*)&sWt[(k + 1) * WS + fq * 4];
        float4 w2 = *(const float4*)&sWt[(k + 2) * WS + fq * 4];
        float4 w3 = *(const float4*)&sWt[(k + 3) * WS + fq * 4];
        float4 x0 = *(const float4*)&sX[(n0 + 0) * XS + k];
        float4 x1 = *(const float4*)&sX[(n0 + 1) * XS + k];
        float4 x2 = *(const float4*)&sX[(n0 + 2) * XS + k];
        float4 x3 = *(const float4*)&sX[(n0 + 3) * XS + k];
        fma4(acc0, x0.x, w0); fma4(acc0, x0.y, w1); fma4(acc0, x0.z, w2); fma4(acc0, x0.w, w3);
        fma4(acc1, x1.x, w0); fma4(acc1, x1.y, w1); fma4(acc1, x1.z, w2); fma4(acc1, x1.w, w3);
        fma4(acc2, x2.x, w0); fma4(acc2, x2.y, w1); fma4(acc2, x2.z, w2); fma4(acc2, x2.w, w3);
        fma4(acc3, x3.x, w0); fma4(acc3, x3.y, w1); fma4(acc3, x3.z, w2); fma4(acc3, x3.w, w3);
    }
    float4 accs[4] = {acc0, acc1, acc2, acc3};
    float4 vs4 = *(const float4*)&avs[fq * 4];
    float4 vd4 = *(const float4*)&avd[fq * 4];
#pragma unroll
    for (int j = 0; j < 4; ++j) {
        int g = nb + n0 + j;
        float ps = accs[j].x * vs4.x + accs[j].y * vs4.y + accs[j].z * vs4.z + accs[j].w * vs4.w;
        float pd = accs[j].x * vd4.x + accs[j].y * vd4.y + accs[j].z * vd4.z + accs[j].w * vd4.w;
#pragma unroll
        for (int off = TF / 2; off; off >>= 1) {
            ps += __shfl_down(ps, off, TF);
            pd += __shfl_down(pd, off, TF);
        }
        if (g < n) {
            if (fq == 0) { as_[g] = ps; ad_[g] = pd; }
            bh4 o;
            o.a = __float2bfloat16(accs[j].x);
            o.b = __float2bfloat16(accs[j].y);
            o.c = __float2bfloat16(accs[j].z);
            o.d = __float2bfloat16(accs[j].w);
            *(bh4*)&H[(size_t)g * FOUT + fq * 4] = o;
        }
    }
}

// ---------------- per-node softmax + aggregate: GROUP-per-node ----------------
// One L-lane group per node (L=16 for FOUT=64, L=8 for FOUT=32); lane gl owns
// features 4*gl..4*gl+3 (uint2 = 4 bf16 of the row). Per 8-edge batch each lane
// issues 8 INDEPENDENT row gathers (indices via intra-group shuffle) -> 8-deep
// memory pipeline regardless of node degree (mean deg = 17 never reached the
// old wave-level deep tier). No cross-group reduce; no LDS; VGPR ~55.
template <int FOUT, bool RELU, bool WRITE_INV>
__global__ __launch_bounds__(256) void k_attn_grp(
    const int* __restrict__ rowptr, const unsigned short* __restrict__ col,
    const float* __restrict__ as_, const float* __restrict__ ad_,
    const __hip_bfloat16* __restrict__ H, const float* __restrict__ bias,
    float* __restrict__ outp, float* __restrict__ inv_out) {
    constexpr int L = (FOUT == 64) ? 16 : 8;   // lanes per node (row = L uint2)
    constexpr int GPW = 64 / L;                // nodes per wave
    int tid = blockIdx.x * 256 + threadIdx.x;
    int wid = tid >> 6;
    int lane = threadIdx.x & 63;
    int grp = lane / L;
    int gl  = lane & (L - 1);
    int node = wid * GPW + grp;
    if (node >= NN) return;

    int start = rowptr[node], end = rowptr[node + 1];
    float adv = ad_[node];
    const uint2* __restrict__ H4 = (const uint2*)H;
    int base = lane & ~(L - 1); // group's first lane (shfl src base)

    float sloc = 0.f;
    float4 acc = make_float4(0.f, 0.f, 0.f, 0.f);
    for (int c = start; c < end; c += 8) {
        int e = c + gl;
        float p = 0.f;
        int sc = 0;
        if (gl < 8 && e < end) {                // lanes gl 0..7 score one edge each
            sc = (int)col[e];
            float v = as_[sc] + adv;
            v = v > 0.f ? v : NEG_SLOPE * v;
            p = __expf(v);
        }
        sloc += p;
        int cnt = end - c; if (cnt > 8) cnt = 8;
        float pp[8]; int ss[8]; uint2 hh[8];
#pragma unroll
        for (int k = 0; k < 8; ++k) {
            pp[k] = __shfl(p, base + k);
            ss[k] = __shfl(sc, base + k);
        }
#pragma unroll
        for (int k = 0; k < 8; ++k) {           // 8 independent gathers in flight
            hh[k] = make_uint2(0u, 0u);
            if (k < cnt) hh[k] = H4[(size_t)ss[k] * L + gl];
        }
#pragma unroll
        for (int k = 0; k < 8; ++k) {           // pp[k]=0 past cnt -> safe
            acc.x = fmaf(pp[k], bflo(hh[k].x), acc.x);
            acc.y = fmaf(pp[k], bfhi(hh[k].x), acc.y);
            acc.z = fmaf(pp[k], bflo(hh[k].y), acc.z);
            acc.w = fmaf(pp[k], bfhi(hh[k].y), acc.w);
        }
    }
    // group-local denominator reduce (offsets stay inside the L-lane group)
#pragma unroll
    for (int off = L / 2; off; off >>= 1) sloc += __shfl_xor(sloc, off);
    float inv = 1.f / (sloc + GAT_EPS);
    if (WRITE_INV && gl == 0) inv_out[node] = inv;

    float4 bb = *(const float4*)&bias[gl * 4];
    float o0 = bb.x + acc.x * inv;
    float o1 = bb.y + acc.y * inv;
    float o2 = bb.z + acc.z * inv;
    float o3 = bb.w + acc.w * inv;
    if (RELU) {
        o0 = fmaxf(o0, 0.f); o1 = fmaxf(o1, 0.f);
        o2 = fmaxf(o2, 0.f); o3 = fmaxf(o3, 0.f);
    }
    *(float4*)&outp[(size_t)node * FOUT + gl * 4] = make_float4(o0, o1, o2, o3);
}

extern "C" void kernel_launch(void* const* d_in, const int* in_sizes, int n_in,
                              void* d_out, int out_size, void* d_ws, size_t ws_size,
                              hipStream_t stream) {
    const float* x  = (const float*)d_in[0];
    const int*   ei = (const int*)d_in[1];
    const float* W1 = (const float*)d_in[2];
    const float* as1 = (const float*)d_in[3];
    const float* ad1 = (const float*)d_in[4];
    const float* b1 = (const float*)d_in[5];
    const float* W2 = (const float*)d_in[6];
    const float* as2 = (const float*)d_in[7];
    const float* ad2 = (const float*)d_in[8];
    const float* b2 = (const float*)d_in[9];
    const float* W3 = (const float*)d_in[10];
    const float* as3 = (const float*)d_in[11];
    const float* ad3 = (const float*)d_in[12];
    const float* b3 = (const float*)d_in[13];

    float* out = (float*)d_out;
    float* out_edges = out;                 // [2, EP]
    float* out_alpha = out + 2 * EP;        // [EP]
    float* out_final = out + 3 * EP;        // [N, 32] = 6.4MB, written only by attn3

    char* w = (char*)d_ws;
    size_t o = 0;
    auto alloc = [&](size_t bytes) { void* p = w + o; o = (o + bytes + 15) & ~15ull; return p; };
    float* as_ = (float*)alloc((size_t)NN * 4);
    float* ad_ = (float*)alloc((size_t)NN * 4);
    float* inv = (float*)alloc((size_t)NN * 4);
    __hip_bfloat16* H = (__hip_bfloat16*)alloc((size_t)NN * 64 * 2); // 6.4MB
    int* rowptr = (int*)alloc((size_t)(NN + 1) * 4);
    unsigned char* rank8 = (unsigned char*)alloc((size_t)EP);        // 0.85MB
    unsigned short* col  = (unsigned short*)alloc((size_t)EP * 2);   // 1.7MB
    unsigned char* chunkoff = (unsigned char*)alloc((size_t)NN * 4); // 200KB
    int* bsum = (int*)alloc(1024);

    const size_t aggBytes  = (size_t)NN * 64 * 4;       // 12.8MB
    const size_t histBytes = (size_t)PB * NN;           // 6.4MB
    float* agg = (ws_size >= o + aggBytes)
        ? (float*)(w + o)
        : (float*)d_in[0];  // safe: layer-1 GEMM consumes x before agg first written
    unsigned char* hist = (ws_size >= o + aggBytes + histBytes)
        ? (unsigned char*)(w + o + aggBytes)
        : (unsigned char*)out_final; // dead until the final attn dispatch

    // --- CSR build: 4 launches ---
    k_p1_hist<<<PB, PT, 0, stream>>>(ei, out_edges, hist, rank8);
    k_p2s1<<<NB, 256, 0, stream>>>(hist, chunkoff, rowptr, bsum);
    k_s23<<<NB, 256, 0, stream>>>(rowptr, bsum);
    k_fill<<<(EP + 255) / 256, 256, 0, stream>>>(ei, rank8, hist, chunkoff, rowptr, col);

    const int nblk64 = (NN + 15) / 16;   // 16 nodes/block (4 waves x 4 nodes)
    const int nblk32 = (NN + 31) / 32;   // 32 nodes/block (4 waves x 8 nodes)

    // layer 1: 128 -> 64, ReLU fused; stores inv[] for the alpha pass
    k_gemm_t<128, 64, 64><<<(NN + 63) / 64, 256, 0, stream>>>(x, W1, as1, ad1, H, as_, ad_, NN);
    k_attn_grp<64, true, true><<<nblk64, 256, 0, stream>>>(rowptr, col, as_, ad_, H, b1,
                                                           agg, inv);
    k_alpha_out<<<(EP + 255) / 256, 256, 0, stream>>>(ei, as_, ad_, inv, out_alpha);

    // layer 2: 64 -> 64, ReLU fused
    k_gemm_t<64, 64, 64><<<(NN + 63) / 64, 256, 0, stream>>>(agg, W2, as2, ad2, H, as_, ad_, NN);
    k_attn_grp<64, true, false><<<nblk64, 256, 0, stream>>>(rowptr, col, as_, ad_, H, b2,
                                                            agg, nullptr);

    // layer 3: 64 -> 32, straight into d_out chunk 2
    k_gemm_t<64, 32, 128><<<(NN + 127) / 128, 256, 0, stream>>>(agg, W3, as3, ad3, H, as_, ad_,
                                                                NN);
    k_attn_grp<32, false, false><<<nblk32, 256, 0, stream>>>(rowptr, col, as_, ad_, H, b3,
                                                             out_final, nullptr);
}